// Round 14
// baseline (329.339 us; speedup 1.0000x reference)
//
#include <hip/hip_runtime.h>
#include <math.h>

#ifndef M_PI
#define M_PI 3.14159265358979323846
#endif

constexpr int S_LEN    = 176400;
constexpr int NFFT     = 2048;
constexpr int NC       = 1024;
constexpr int HOP_     = 441;
constexpr int T_FRAMES = 401;
constexpr int F_BINS   = 1025;
constexpr int F_STRIDE = 1028;     // fp32 spec row stride (16B aligned)
constexpr int N_CH     = 64;
constexpr float EPS4_  = 4e-8f;    // 4*EPS (0.5 factored out of sqrt exactly)
// scaled-sum SSIM constants: K1 = C1*49^2, K2 = C2*48*49 (R13-validated)
constexpr float K1_    = 0.96040f;
constexpr float K2_    = 8.46720f;

// workspace float offsets
constexpr int WIN_OFF  = 0;        // float[2048] hann window
constexpr int TWG_OFF  = 2048;     // float2[768]  tw[e] = exp(-2pi i e/1024)
constexpr int UTW_OFF  = 3584;     // float2[1025] exp(-i pi r/1024)
constexpr int SPEC_OFF = 5696;

// ssim wave decomposition: R11/R13 config frozen (best: 326.1us)
constexpr int ROWS_PW   = 24;
constexpr int NCHUNKS_R = 17;      // ceil(395/24)
constexpr int BANDS     = 5;
constexpr int BAND_ADV  = 248;     // 62 producing lanes * 4 cols

// native 2xf32 vector type -> VGPR pair, usable as inline-asm operand
typedef float vf2 __attribute__((ext_vector_type(2)));

// LDS bank swizzle: phys(i) = i ^ ((i>>2)&15) ^ ((i>>6)&15) (bijective,
// conflict-checked per access pattern in R2).
__device__ __forceinline__ int phys(int i) { return i ^ ((i >> 2) & 15) ^ ((i >> 6) & 15); }

// ---- packed-f32 complex primitives (VOP3P), absmax-verified R7-R13.
__device__ __forceinline__ vf2 pk_add(vf2 a, vf2 b) {
    vf2 r; asm("v_pk_add_f32 %0, %1, %2" : "=v"(r) : "v"(a), "v"(b)); return r;
}
__device__ __forceinline__ vf2 pk_sub(vf2 a, vf2 b) {
    vf2 r; asm("v_pk_add_f32 %0, %1, %2 neg_lo:[0,1] neg_hi:[0,1]" : "=v"(r) : "v"(a), "v"(b)); return r;
}
// {b.x + d.y, b.y - d.x}  == b - i*d
__device__ __forceinline__ vf2 pk_sub_i(vf2 b, vf2 d) {
    vf2 r; asm("v_pk_add_f32 %0, %1, %2 op_sel:[0,1] op_sel_hi:[1,0] neg_hi:[0,1]"
               : "=v"(r) : "v"(b), "v"(d)); return r;
}
// {b.x - d.y, b.y + d.x}  == b + i*d
__device__ __forceinline__ vf2 pk_add_i(vf2 b, vf2 d) {
    vf2 r; asm("v_pk_add_f32 %0, %1, %2 op_sel:[0,1] op_sel_hi:[1,0] neg_lo:[0,1]"
               : "=v"(r) : "v"(b), "v"(d)); return r;
}
// complex multiply y*w
__device__ __forceinline__ vf2 pk_cmul(vf2 y, vf2 w) {
    vf2 t, r;
    asm("v_pk_mul_f32 %0, %1, %2 op_sel:[0,0] op_sel_hi:[0,1]"
        : "=v"(t) : "v"(y), "v"(w));
    asm("v_pk_fma_f32 %0, %1, %2, %3 op_sel:[1,1,0] op_sel_hi:[1,0,1] neg_lo:[1,0,0]"
        : "=v"(r) : "v"(y), "v"(w), "v"(t));
    return r;
}
// unpack even part: {a.x+b.x, a.y-b.y}   (defaults: op_sel [0,0], op_sel_hi [1,1])
__device__ __forceinline__ vf2 pk_even(vf2 a, vf2 b) {
    vf2 r; asm("v_pk_add_f32 %0, %1, %2 neg_hi:[0,1]" : "=v"(r) : "v"(a), "v"(b)); return r;
}
// unpack odd part: {a.y+b.y, b.x-a.x}
__device__ __forceinline__ vf2 pk_odd(vf2 a, vf2 b) {
    vf2 r; asm("v_pk_add_f32 %0, %1, %2 op_sel:[1,1] op_sel_hi:[0,0] neg_hi:[1,0]"
               : "=v"(r) : "v"(a), "v"(b)); return r;
}

__global__ __launch_bounds__(256) void init_tables_kernel(float* __restrict__ ws, float* __restrict__ out) {
    const int idx = blockIdx.x * 256 + threadIdx.x;
    if (idx < 64) out[idx] = 0.0f;
    if (idx < NFFT) {
        ws[WIN_OFF + idx] = 0.5f - 0.5f * cosf((float)(2.0 * M_PI / NFFT) * (float)idx);
    }
    if (idx < 768) {
        float ang = -2.0f * (float)M_PI * (float)idx / (float)NC;
        float s, c; sincosf(ang, &s, &c);
        ws[TWG_OFF + 2*idx] = c; ws[TWG_OFF + 2*idx+1] = s;
    }
    if (idx < F_BINS) {
        float ang = -(float)M_PI * (float)idx / (float)NC;
        float s, c; sincosf(ang, &s, &c);
        ws[UTW_OFF + 2*idx] = c; ws[UTW_OFF + 2*idx+1] = s;
    }
}

// Radix-4 DIF butterfly core (registers in, registers out)
__device__ __forceinline__ void r4_core(
    vf2 x0c, vf2 x1c, vf2 x2c, vf2 x3c,
    vf2& y0, vf2& y1, vf2& y2, vf2& y3)
{
    vf2 a = pk_add(x0c, x2c);
    vf2 b = pk_sub(x0c, x2c);
    vf2 c = pk_add(x1c, x3c);
    vf2 d = pk_sub(x1c, x3c);
    y0 = pk_add(a, c);
    y2 = pk_sub(a, c);
    y1 = pk_sub_i(b, d);
    y3 = pk_add_i(b, d);
}

// In-place radix-4 DIF butterfly (LDS version, stages 1..4 + boundary stage 0)
__device__ __forceinline__ void r4_dif_inplace(
    vf2* __restrict__ A, int r0, int r1, int r2, int r3,
    vf2 w1, vf2 w2, vf2 w3, bool tw)
{
    vf2 y0, y1, y2, y3;
    r4_core(A[r0], A[r1], A[r2], A[r3], y0, y1, y2, y3);
    A[r0] = y0;
    A[r1] = tw ? pk_cmul(y1, w1) : y1;
    A[r2] = tw ? pk_cmul(y2, w2) : y2;
    A[r3] = tw ? pk_cmul(y3, w3) : y3;
}

// Dual 1024-pt in-place radix-4 DIF; one block = frame t of channel ch, both
// tensors.  16 KB LDS -> 8 blocks/CU.  R14: pack + stage 0 FUSED in registers
// for interior frames (395/401): stage 0 reads exactly complex {tid+256k}, so
// the thread loads those 4 complex per FFT from global (same 8 dword loads as
// the old pack loop), windows them, butterflies in regs, and writes only 4 b64
// results.  Saves 8 LDS-b32-writes + 4 b64-reads per FFT + 1 barrier (6->5)
// + the pack address math.  Unpack rewritten in packed-f32 (pk_even/pk_odd/
// pk_cmul; 0.5 factored out of sqrt exactly, EPS -> 4*EPS).
__global__ __launch_bounds__(256, 8) void stft_mag_kernel(
    const float* __restrict__ x0, const float* __restrict__ x1,
    float* __restrict__ ws, int ch0, int chbase, int nlay, int swizzle)
{
    __shared__ vf2 buf[2 * NC];   // FFT0 at [0,NC), FFT1 at [NC,2NC)

    const int tid = threadIdx.x;

    int ch, t;
    if (swizzle) {
        int g = blockIdx.x;
        ch = ch0 + (g & 7) * 8 + ((g >> 3) & 7);
        t  = g >> 6;
    } else {
        t  = blockIdx.x;
        ch = ch0 + blockIdx.y;
    }

    const float* __restrict__ xin0 = x0 + (size_t)ch * S_LEN;
    const float* __restrict__ xin1 = x1 + (size_t)ch * S_LEN;
    const float* __restrict__ win  = ws + WIN_OFF;
    const vf2*   __restrict__ twg  = (const vf2*)(ws + TWG_OFF);
    const vf2*   __restrict__ utw  = (const vf2*)(ws + UTW_OFF);

    const int base = t * HOP_ - NFFT / 2;

    if (base >= 0 && base + NFFT <= S_LEN) {
        // ---- fused pack + stage 0 (registers), interior fast path.
        // stage 0 geometry: q = tid, i0 = tid, slots {tid+256k}, e = tid.
        vf2 a0[4], a1[4];
        #pragma unroll
        for (int k = 0; k < 4; ++k) {
            const int ci = tid + 256 * k;
            const int n2 = 2 * ci;
            const int j  = base + n2;
            vf2 w2v = *(const vf2*)(win + n2);       // win[n2], win[n2+1] (8B aligned)
            float xa = xin0[j], xb = xin0[j + 1];
            float ya = xin1[j], yb = xin1[j + 1];
            a0[k].x = xa * w2v.x; a0[k].y = xb * w2v.y;
            a1[k].x = ya * w2v.x; a1[k].y = yb * w2v.y;
        }
        const vf2 w1 = twg[tid];
        const vf2 w2 = twg[2 * tid];
        const vf2 w3 = twg[3 * tid];
        const int r0 = phys(tid);
        const int r1 = phys(tid + 256);
        const int r2 = phys(tid + 512);
        const int r3 = phys(tid + 768);
        {
            vf2 y0, y1, y2, y3;
            r4_core(a0[0], a0[1], a0[2], a0[3], y0, y1, y2, y3);
            buf[r0] = y0;
            buf[r1] = pk_cmul(y1, w1);
            buf[r2] = pk_cmul(y2, w2);
            buf[r3] = pk_cmul(y3, w3);
        }
        {
            vf2 y0, y1, y2, y3;
            r4_core(a1[0], a1[1], a1[2], a1[3], y0, y1, y2, y3);
            buf[NC + r0] = y0;
            buf[NC + r1] = pk_cmul(y1, w1);
            buf[NC + r2] = pk_cmul(y2, w2);
            buf[NC + r3] = pk_cmul(y3, w3);
        }
    } else {
        // ---- boundary frames (6/401): reflect pack to LDS + LDS stage 0
        float* fA0 = (float*)buf;
        float* fA1 = (float*)(buf + NC);
        #pragma unroll
        for (int k = 0; k < NFFT / 256; ++k) {
            int n = k * 256 + tid;
            int j = base + n;
            j = (j < 0) ? -j : j;
            j = (j >= S_LEN) ? (2 * S_LEN - 2 - j) : j;
            float w = win[n];
            int p = 2 * phys(n >> 1) + (n & 1);
            fA0[p] = xin0[j] * w;
            fA1[p] = xin1[j] * w;
        }
        __syncthreads();
        const vf2 w1 = twg[tid];
        const vf2 w2 = twg[2 * tid];
        const vf2 w3 = twg[3 * tid];
        const int r0 = phys(tid);
        const int r1 = phys(tid + 256);
        const int r2 = phys(tid + 512);
        const int r3 = phys(tid + 768);
        r4_dif_inplace(buf,      r0, r1, r2, r3, w1, w2, w3, true);
        r4_dif_inplace(buf + NC, r0, r1, r2, r3, w1, w2, w3, true);
    }
    __syncthreads();

    // ---- stages 1..4 in LDS, x2 FFTs
    #pragma unroll
    for (int s = 1; s < 5; ++s) {
        const int M  = 256 >> (2 * s);
        const int q  = tid & (M - 1);
        const int e  = q << (2 * s);
        const int i0 = 4 * (tid - q) + q;

        const int r0 = phys(i0);
        const int r1 = phys(i0 + M);
        const int r2 = phys(i0 + 2 * M);
        const int r3 = phys(i0 + 3 * M);

        vf2 w1, w2, w3;
        if (s < 4) {
            w1 = twg[e];
            w2 = twg[2 * e];
            w3 = twg[3 * e];
        } else {
            w1.x = 1.0f; w1.y = 0.0f; w2 = w1; w3 = w1;
        }

        r4_dif_inplace(buf,      r0, r1, r2, r3, w1, w2, w3, s < 4);
        r4_dif_inplace(buf + NC, r0, r1, r2, r3, w1, w2, w3, s < 4);

        __syncthreads();
    }

    // ---- real-FFT unpack + magnitude, packed-f32, fp32 coalesced stores
    const size_t perT = (size_t)T_FRAMES * F_STRIDE;
    float* __restrict__ sout0 =
        ws + SPEC_OFF + (size_t)(ch - chbase) * perT + (size_t)t * F_STRIDE;
    float* __restrict__ sout1 = sout0 + (size_t)nlay * perT;

    const int R8 = ((tid & 3) << 6) | ((tid & 12) << 2) | ((tid >> 2) & 12) | ((tid >> 6) & 3);

    #pragma unroll
    for (int k = 0; k < 5; ++k) {
        int r = k * 256 + tid;
        if (k < 4 || tid == 0) {
            const int ra = (k < 4) ? ((R8 << 2) | k) : 0;          // rev4(r & 1023)
            const int rn = (NC - r) & (NC - 1);
            const int rb = ((rn & 3) << 8) | ((rn & 12) << 4) | (rn & 48)
                         | ((rn >> 4) & 12) | ((rn >> 8) & 3);     // rev4(rn)
            const int ia = phys(ra);
            const int ib = phys(rb);
            vf2 wu = utw[r];

            {   // tensor 0: X = 0.5*(E + O*wu); |X| = 0.5*sqrt(max(M^2, 4EPS))
                vf2 E = pk_even(buf[ia], buf[ib]);
                vf2 O = pk_odd (buf[ia], buf[ib]);
                vf2 M = pk_add(E, pk_cmul(O, wu));
                sout0[r] = 0.5f * sqrtf(fmaxf(M.x * M.x + M.y * M.y, EPS4_));
            }
            {   // tensor 1
                vf2 E = pk_even(buf[NC + ia], buf[NC + ib]);
                vf2 O = pk_odd (buf[NC + ia], buf[NC + ib]);
                vf2 M = pk_add(E, pk_cmul(O, wu));
                sout1[r] = 0.5f * sqrtf(fmaxf(M.x * M.x + M.y * M.y, EPS4_));
            }
        }
    }
}

// SSIM v8 (R13, frozen): 4 cols/lane, 5 bands, ROWS_PW 24, read-once ring,
// 1-ahead prefetch, 4-stat fusion, scaled-sum formula, rcp div.
#define HWIN7(sarr, W) {                                                     \
    float p0 = sarr[0], p01 = p0 + sarr[1], p012 = p01 + sarr[2],            \
          P = p012 + sarr[3];                                                \
    float a1 = __shfl_down(p012, 1, 64);                                     \
    float A1 = __shfl_down(P,    1, 64);                                     \
    float b0 = __shfl_down(p0,   2, 64);                                     \
    float b1 = __shfl_down(p01,  2, 64);                                     \
    W[0] = P + a1;                                                           \
    W[1] = P - p0 + A1;                                                      \
    W[2] = W[1] - sarr[1] + b0;                                              \
    W[3] = W[2] - sarr[2] + (b1 - b0);                                       \
}

__global__ __launch_bounds__(256) void ssim_kernel(
    const float* __restrict__ ws, float* __restrict__ out,
    int ch0, int nch)
{
    const int tid  = threadIdx.x;
    const int wid  = blockIdx.x * 4 + (tid >> 6);
    const int lane = tid & 63;
    const int total = nch * BANDS * NCHUNKS_R;
    if (wid >= total) return;

    const int cg    = wid / (BANDS * NCHUNKS_R);
    const int rem   = wid - cg * (BANDS * NCHUNKS_R);
    const int band  = rem / NCHUNKS_R;
    const int chunk = rem - band * NCHUNKS_R;

    const int t0 = 3 + chunk * ROWS_PW;
    const int t1 = min(t0 + ROWS_PW, T_FRAMES - 3);   // <= 398

    const int cb = band * BAND_ADV;
    int c4 = cb + 4 * lane;
    if (c4 > 1024) c4 = 1024;      // stay inside the 1028-float row (no OOB)

    const size_t perT = (size_t)T_FRAMES * F_STRIDE;
    const float* __restrict__ X = ws + SPEC_OFF + (size_t)cg * perT + c4;
    const float* __restrict__ Y = ws + SPEC_OFF + ((size_t)nch + cg) * perT + c4;

    const int  fo      = cb + 3 + 4 * lane;   // first output col of this lane
    const bool lane_ok = (lane <= 61);

    // 4 windowed stats: sx, sy, s2 = sxx+syy, sxy
    float sx[4] = {0,0,0,0}, sy[4] = {0,0,0,0}, s2[4] = {0,0,0,0},
          sxy[4] = {0,0,0,0};
    float rgx[6][4], rgy[6][4];    // ring of raw (x,y) rows t-3..t+2

    #pragma unroll
    for (int w = 0; w < 6; ++w) {
        const int rr = t0 - 3 + w;
        float4 xv = *(const float4*)(X + (size_t)rr * F_STRIDE);
        float4 yv = *(const float4*)(Y + (size_t)rr * F_STRIDE);
        float xa[4] = {xv.x, xv.y, xv.z, xv.w}, ya[4] = {yv.x, yv.y, yv.z, yv.w};
        #pragma unroll
        for (int c = 0; c < 4; ++c) {
            sx[c] += xa[c]; sy[c] += ya[c];
            s2[c] += xa[c]*xa[c] + ya[c]*ya[c];
            sxy[c] += xa[c]*ya[c];
            rgx[w][c] = xa[c]; rgy[w][c] = ya[c];
        }
    }

    float4 cxa = *(const float4*)(X + (size_t)(t0 + 3) * F_STRIDE);
    float4 cya = *(const float4*)(Y + (size_t)(t0 + 3) * F_STRIDE);

    double acc = 0.0;

    #pragma unroll 1
    for (int tb = t0; tb < t1; tb += 6) {
        #pragma unroll
        for (int j = 0; j < 6; ++j) {
            const int t = tb + j;
            const int tn = min(t + 4, T_FRAMES - 1);
            float4 nxa = *(const float4*)(X + (size_t)tn * F_STRIDE);
            float4 nya = *(const float4*)(Y + (size_t)tn * F_STRIDE);

            float xa[4] = {cxa.x, cxa.y, cxa.z, cxa.w};
            float ya[4] = {cya.x, cya.y, cya.z, cya.w};

            // add row t+3 (prefetched)
            #pragma unroll
            for (int c = 0; c < 4; ++c) {
                sx[c] += xa[c]; sy[c] += ya[c];
                s2[c] += xa[c]*xa[c] + ya[c]*ya[c];
                sxy[c] += xa[c]*ya[c];
            }

            float wx[4], wy[4], w2[4], wxy[4];
            HWIN7(sx,  wx);
            HWIN7(sy,  wy);
            HWIN7(s2,  w2);
            HWIN7(sxy, wxy);

            const bool live = (t < t1);
            float rowacc = 0.0f;
            #pragma unroll
            for (int c = 0; c < 4; ++c) {
                if (live && lane_ok && (fo + c <= 1021)) {
                    float p = wx[c] * wy[c];                       // wx*wy
                    float q = fmaf(wx[c], wx[c], wy[c]*wy[c]);     // wx^2+wy^2
                    float r = fmaf(49.f, wxy[c], -p);              // 49wxy - p
                    float s = fmaf(49.f, w2[c],  -q);              // 49w2  - q
                    float num = fmaf(2.f, p, K1_) * fmaf(2.f, r, K2_);
                    float den = (q + K1_) * (s + K2_);
                    rowacc = fmaf(num, __builtin_amdgcn_rcpf(den), rowacc);
                }
            }
            acc += (double)rowacc;

            // subtract row t-3 from the ring (static slot j), store new row
            #pragma unroll
            for (int c = 0; c < 4; ++c) {
                float bx_ = rgx[j][c], by_ = rgy[j][c];
                sx[c]  -= bx_;      sy[c]  -= by_;
                s2[c]  -= bx_*bx_ + by_*by_;
                sxy[c] -= bx_*by_;
                rgx[j][c] = xa[c];  rgy[j][c] = ya[c];
            }

            cxa = nxa; cya = nya;
        }
    }

    #pragma unroll
    for (int off = 32; off > 0; off >>= 1) acc += __shfl_down(acc, off, 64);
    if (lane == 0) {
        atomicAdd(&out[ch0 + cg], (float)(acc / (395.0 * 1019.0)));
    }
}

extern "C" void kernel_launch(void* const* d_in, const int* in_sizes, int n_in,
                              void* d_out, int out_size, void* d_ws, size_t ws_size,
                              hipStream_t stream) {
    const float* x0 = (const float*)d_in[0];   // output
    const float* x1 = (const float*)d_in[1];   // target
    float* out = (float*)d_out;
    float* ws  = (float*)d_ws;

    const size_t table_bytes  = (size_t)SPEC_OFF * sizeof(float);
    const size_t per_ch_bytes = (size_t)2 * T_FRAMES * F_STRIDE * sizeof(float);
    int G = (int)((ws_size - table_bytes) / per_ch_bytes);
    if (G > N_CH) G = N_CH;
    if (G < 1)    G = 1;

    init_tables_kernel<<<dim3(16), dim3(256), 0, stream>>>(ws, out);

    if (G >= N_CH) {
        // single swizzled 64-channel stft + single ssim (3 dispatches total)
        stft_mag_kernel<<<dim3(T_FRAMES * 64), dim3(256), 0, stream>>>(x0, x1, ws, 0, 0, N_CH, 1);
        const int nwaves = N_CH * BANDS * NCHUNKS_R;
        ssim_kernel<<<dim3((nwaves + 3) / 4), dim3(256), 0, stream>>>(ws, out, 0, N_CH);
    } else {
        for (int ch0 = 0; ch0 < N_CH; ch0 += G) {
            const int nch = (N_CH - ch0 < G) ? (N_CH - ch0) : G;
            stft_mag_kernel<<<dim3(T_FRAMES, nch), dim3(256), 0, stream>>>(x0, x1, ws, ch0, ch0, nch, 0);
            const int nwaves = nch * BANDS * NCHUNKS_R;
            ssim_kernel<<<dim3((nwaves + 3) / 4), dim3(256), 0, stream>>>(ws, out, ch0, nch);
        }
    }
}

// Round 15
// 324.493 us; speedup vs baseline: 1.0149x; 1.0149x over previous
//
#include <hip/hip_runtime.h>
#include <math.h>

#ifndef M_PI
#define M_PI 3.14159265358979323846
#endif

constexpr int S_LEN    = 176400;
constexpr int NFFT     = 2048;
constexpr int NC       = 1024;
constexpr int HOP_     = 441;
constexpr int T_FRAMES = 401;
constexpr int F_BINS   = 1025;
constexpr int F_STRIDE = 1028;     // fp32 spec row stride (16B aligned)
constexpr int N_CH     = 64;
constexpr float EPS_   = 1e-8f;
// scaled-sum SSIM constants: K1 = C1*49^2, K2 = C2*48*49 (R13-validated)
constexpr float K1_    = 0.96040f;
constexpr float K2_    = 8.46720f;

// workspace float offsets
constexpr int WIN_OFF  = 0;        // float[2048] hann window
constexpr int TWG_OFF  = 2048;     // float2[768]  tw[e] = exp(-2pi i e/1024)
constexpr int UTW_OFF  = 3584;     // float2[1025] exp(-i pi r/1024)
constexpr int SPEC_OFF = 5696;

// ssim wave decomposition: R11/R13 config (best measured: 326.1us)
constexpr int ROWS_PW   = 24;
constexpr int NCHUNKS_R = 17;      // ceil(395/24)
constexpr int BANDS     = 5;
constexpr int BAND_ADV  = 248;     // 62 producing lanes * 4 cols

// native 2xf32 vector type -> VGPR pair, usable as inline-asm operand
typedef float vf2 __attribute__((ext_vector_type(2)));

// LDS bank swizzle: phys(i) = i ^ ((i>>2)&15) ^ ((i>>6)&15) (bijective,
// conflict-checked per access pattern in R2).
__device__ __forceinline__ int phys(int i) { return i ^ ((i >> 2) & 15) ^ ((i >> 6) & 15); }

// ---- packed-f32 complex primitives (VOP3P), absmax-verified R7-R14.
__device__ __forceinline__ vf2 pk_add(vf2 a, vf2 b) {
    vf2 r; asm("v_pk_add_f32 %0, %1, %2" : "=v"(r) : "v"(a), "v"(b)); return r;
}
__device__ __forceinline__ vf2 pk_sub(vf2 a, vf2 b) {
    vf2 r; asm("v_pk_add_f32 %0, %1, %2 neg_lo:[0,1] neg_hi:[0,1]" : "=v"(r) : "v"(a), "v"(b)); return r;
}
// {b.x + d.y, b.y - d.x}  == b - i*d
__device__ __forceinline__ vf2 pk_sub_i(vf2 b, vf2 d) {
    vf2 r; asm("v_pk_add_f32 %0, %1, %2 op_sel:[0,1] op_sel_hi:[1,0] neg_hi:[0,1]"
               : "=v"(r) : "v"(b), "v"(d)); return r;
}
// {b.x - d.y, b.y + d.x}  == b + i*d
__device__ __forceinline__ vf2 pk_add_i(vf2 b, vf2 d) {
    vf2 r; asm("v_pk_add_f32 %0, %1, %2 op_sel:[0,1] op_sel_hi:[1,0] neg_lo:[0,1]"
               : "=v"(r) : "v"(b), "v"(d)); return r;
}
// complex multiply y*w
__device__ __forceinline__ vf2 pk_cmul(vf2 y, vf2 w) {
    vf2 t, r;
    asm("v_pk_mul_f32 %0, %1, %2 op_sel:[0,0] op_sel_hi:[0,1]"
        : "=v"(t) : "v"(y), "v"(w));
    asm("v_pk_fma_f32 %0, %1, %2, %3 op_sel:[1,1,0] op_sel_hi:[1,0,1] neg_lo:[1,0,0]"
        : "=v"(r) : "v"(y), "v"(w), "v"(t));
    return r;
}

__global__ __launch_bounds__(256) void init_tables_kernel(float* __restrict__ ws, float* __restrict__ out) {
    const int idx = blockIdx.x * 256 + threadIdx.x;
    if (idx < 64) out[idx] = 0.0f;
    if (idx < NFFT) {
        ws[WIN_OFF + idx] = 0.5f - 0.5f * cosf((float)(2.0 * M_PI / NFFT) * (float)idx);
    }
    if (idx < 768) {
        float ang = -2.0f * (float)M_PI * (float)idx / (float)NC;
        float s, c; sincosf(ang, &s, &c);
        ws[TWG_OFF + 2*idx] = c; ws[TWG_OFF + 2*idx+1] = s;
    }
    if (idx < F_BINS) {
        float ang = -(float)M_PI * (float)idx / (float)NC;
        float s, c; sincosf(ang, &s, &c);
        ws[UTW_OFF + 2*idx] = c; ws[UTW_OFF + 2*idx+1] = s;
    }
}

// In-place radix-4 DIF butterfly, packed-f32 (semantics identical to R2-R5)
__device__ __forceinline__ void r4_dif_inplace(
    vf2* __restrict__ A, int r0, int r1, int r2, int r3,
    vf2 w1, vf2 w2, vf2 w3, bool tw)
{
    vf2 x0c = A[r0];
    vf2 x1c = A[r1];
    vf2 x2c = A[r2];
    vf2 x3c = A[r3];

    vf2 a = pk_add(x0c, x2c);
    vf2 b = pk_sub(x0c, x2c);
    vf2 c = pk_add(x1c, x3c);
    vf2 d = pk_sub(x1c, x3c);

    vf2 y0 = pk_add(a, c);
    vf2 y2 = pk_sub(a, c);
    vf2 y1 = pk_sub_i(b, d);
    vf2 y3 = pk_add_i(b, d);

    A[r0] = y0;
    A[r1] = tw ? pk_cmul(y1, w1) : y1;
    A[r2] = tw ? pk_cmul(y2, w2) : y2;
    A[r3] = tw ? pk_cmul(y3, w3) : y3;
}

// Dual 1024-pt in-place radix-4 DIF; one block = frame t of channel ch, both
// tensors.  16 KB LDS -> 8 blocks/CU.  Single swizzled 64-ch dispatch.
// R14 post-mortem: duration invariant to VALU work (78->54% busy, ~190us
// pinned) -> structure-bound on LDS round-trip + barrier chain.  R13 form
// restored (best measured).
__global__ __launch_bounds__(256, 8) void stft_mag_kernel(
    const float* __restrict__ x0, const float* __restrict__ x1,
    float* __restrict__ ws, int ch0, int chbase, int nlay, int swizzle)
{
    __shared__ vf2 buf[2 * NC];   // FFT0 at [0,NC), FFT1 at [NC,2NC)

    const int tid = threadIdx.x;

    int ch, t;
    if (swizzle) {
        int g = blockIdx.x;
        ch = ch0 + (g & 7) * 8 + ((g >> 3) & 7);
        t  = g >> 6;
    } else {
        t  = blockIdx.x;
        ch = ch0 + blockIdx.y;
    }

    const float* __restrict__ xin0 = x0 + (size_t)ch * S_LEN;
    const float* __restrict__ xin1 = x1 + (size_t)ch * S_LEN;
    const float* __restrict__ win  = ws + WIN_OFF;
    const vf2*   __restrict__ twg  = (const vf2*)(ws + TWG_OFF);
    const vf2*   __restrict__ utw  = (const vf2*)(ws + UTW_OFF);

    // ---- pack: flat float index n over [0,2048); complex ci = n>>1 (swizzled)
    const int base = t * HOP_ - NFFT / 2;
    float* fA0 = (float*)buf;             // FFT0
    float* fA1 = (float*)(buf + NC);      // FFT1 (+8 KB)
    if (base >= 0 && base + NFFT <= S_LEN) {
        #pragma unroll
        for (int k = 0; k < NFFT / 256; ++k) {
            int n = k * 256 + tid;
            int j = base + n;
            float w = win[n];
            int p = 2 * phys(n >> 1) + (n & 1);
            fA0[p] = xin0[j] * w;
            fA1[p] = xin1[j] * w;
        }
    } else {
        #pragma unroll
        for (int k = 0; k < NFFT / 256; ++k) {
            int n = k * 256 + tid;
            int j = base + n;
            j = (j < 0) ? -j : j;
            j = (j >= S_LEN) ? (2 * S_LEN - 2 - j) : j;
            float w = win[n];
            int p = 2 * phys(n >> 1) + (n & 1);
            fA0[p] = xin0[j] * w;
            fA1[p] = xin1[j] * w;
        }
    }
    __syncthreads();

    // ---- 5-stage in-place radix-4 DIF, x2 FFTs
    #pragma unroll
    for (int s = 0; s < 5; ++s) {
        const int M  = 256 >> (2 * s);
        const int q  = tid & (M - 1);
        const int e  = q << (2 * s);
        const int i0 = 4 * (tid - q) + q;

        const int r0 = phys(i0);
        const int r1 = phys(i0 + M);
        const int r2 = phys(i0 + 2 * M);
        const int r3 = phys(i0 + 3 * M);

        vf2 w1, w2, w3;
        if (s < 4) {
            w1 = twg[e];
            w2 = twg[2 * e];
            w3 = twg[3 * e];
        } else {
            w1.x = 1.0f; w1.y = 0.0f; w2 = w1; w3 = w1;
        }

        r4_dif_inplace(buf,      r0, r1, r2, r3, w1, w2, w3, s < 4);
        r4_dif_inplace(buf + NC, r0, r1, r2, r3, w1, w2, w3, s < 4);

        __syncthreads();
    }

    // ---- real-FFT unpack + magnitude + fp32 coalesced stores (both tensors)
    const size_t perT = (size_t)T_FRAMES * F_STRIDE;
    float* __restrict__ sout0 =
        ws + SPEC_OFF + (size_t)(ch - chbase) * perT + (size_t)t * F_STRIDE;
    float* __restrict__ sout1 = sout0 + (size_t)nlay * perT;

    const int R8 = ((tid & 3) << 6) | ((tid & 12) << 2) | ((tid >> 2) & 12) | ((tid >> 6) & 3);

    #pragma unroll
    for (int k = 0; k < 5; ++k) {
        int r = k * 256 + tid;
        if (k < 4 || tid == 0) {
            const int ra = (k < 4) ? ((R8 << 2) | k) : 0;          // rev4(r & 1023)
            const int rn = (NC - r) & (NC - 1);
            const int rb = ((rn & 3) << 8) | ((rn & 12) << 4) | (rn & 48)
                         | ((rn >> 4) & 12) | ((rn >> 8) & 3);     // rev4(rn)
            const int ia = phys(ra);
            const int ib = phys(rb);
            vf2 wu = utw[r];

            {   // tensor 0
                vf2 Zr = buf[ia];
                vf2 Zn = buf[ib];
                float Ex = 0.5f * (Zr.x + Zn.x);
                float Ey = 0.5f * (Zr.y - Zn.y);
                float Ox = 0.5f * (Zr.y + Zn.y);
                float Oy = 0.5f * (Zn.x - Zr.x);
                float Xx = Ex + wu.x * Ox - wu.y * Oy;
                float Xy = Ey + wu.x * Oy + wu.y * Ox;
                sout0[r] = sqrtf(fmaxf(Xx * Xx + Xy * Xy, EPS_));
            }
            {   // tensor 1
                vf2 Zr = buf[NC + ia];
                vf2 Zn = buf[NC + ib];
                float Ex = 0.5f * (Zr.x + Zn.x);
                float Ey = 0.5f * (Zr.y - Zn.y);
                float Ox = 0.5f * (Zr.y + Zn.y);
                float Oy = 0.5f * (Zn.x - Zr.x);
                float Xx = Ex + wu.x * Ox - wu.y * Oy;
                float Xy = Ey + wu.x * Oy + wu.y * Ox;
                sout1[r] = sqrtf(fmaxf(Xx * Xx + Xy * Xy, EPS_));
            }
        }
    }
}

// SSIM v8 (R13, best measured): 4 cols/lane, 5 bands, ROWS_PW 24, read-once
// ring, 1-ahead prefetch, 4-stat fusion, scaled-sum formula, rcp div.
#define HWIN7(sarr, W) {                                                     \
    float p0 = sarr[0], p01 = p0 + sarr[1], p012 = p01 + sarr[2],            \
          P = p012 + sarr[3];                                                \
    float a1 = __shfl_down(p012, 1, 64);                                     \
    float A1 = __shfl_down(P,    1, 64);                                     \
    float b0 = __shfl_down(p0,   2, 64);                                     \
    float b1 = __shfl_down(p01,  2, 64);                                     \
    W[0] = P + a1;                                                           \
    W[1] = P - p0 + A1;                                                      \
    W[2] = W[1] - sarr[1] + b0;                                              \
    W[3] = W[2] - sarr[2] + (b1 - b0);                                       \
}

__global__ __launch_bounds__(256) void ssim_kernel(
    const float* __restrict__ ws, float* __restrict__ out,
    int ch0, int nch)
{
    const int tid  = threadIdx.x;
    const int wid  = blockIdx.x * 4 + (tid >> 6);
    const int lane = tid & 63;
    const int total = nch * BANDS * NCHUNKS_R;
    if (wid >= total) return;

    const int cg    = wid / (BANDS * NCHUNKS_R);
    const int rem   = wid - cg * (BANDS * NCHUNKS_R);
    const int band  = rem / NCHUNKS_R;
    const int chunk = rem - band * NCHUNKS_R;

    const int t0 = 3 + chunk * ROWS_PW;
    const int t1 = min(t0 + ROWS_PW, T_FRAMES - 3);   // <= 398

    const int cb = band * BAND_ADV;
    int c4 = cb + 4 * lane;
    if (c4 > 1024) c4 = 1024;      // stay inside the 1028-float row (no OOB)

    const size_t perT = (size_t)T_FRAMES * F_STRIDE;
    const float* __restrict__ X = ws + SPEC_OFF + (size_t)cg * perT + c4;
    const float* __restrict__ Y = ws + SPEC_OFF + ((size_t)nch + cg) * perT + c4;

    const int  fo      = cb + 3 + 4 * lane;   // first output col of this lane
    const bool lane_ok = (lane <= 61);

    // 4 windowed stats: sx, sy, s2 = sxx+syy, sxy
    float sx[4] = {0,0,0,0}, sy[4] = {0,0,0,0}, s2[4] = {0,0,0,0},
          sxy[4] = {0,0,0,0};
    float rgx[6][4], rgy[6][4];    // ring of raw (x,y) rows t-3..t+2

    #pragma unroll
    for (int w = 0; w < 6; ++w) {
        const int rr = t0 - 3 + w;
        float4 xv = *(const float4*)(X + (size_t)rr * F_STRIDE);
        float4 yv = *(const float4*)(Y + (size_t)rr * F_STRIDE);
        float xa[4] = {xv.x, xv.y, xv.z, xv.w}, ya[4] = {yv.x, yv.y, yv.z, yv.w};
        #pragma unroll
        for (int c = 0; c < 4; ++c) {
            sx[c] += xa[c]; sy[c] += ya[c];
            s2[c] += xa[c]*xa[c] + ya[c]*ya[c];
            sxy[c] += xa[c]*ya[c];
            rgx[w][c] = xa[c]; rgy[w][c] = ya[c];
        }
    }

    float4 cxa = *(const float4*)(X + (size_t)(t0 + 3) * F_STRIDE);
    float4 cya = *(const float4*)(Y + (size_t)(t0 + 3) * F_STRIDE);

    double acc = 0.0;

    #pragma unroll 1
    for (int tb = t0; tb < t1; tb += 6) {
        #pragma unroll
        for (int j = 0; j < 6; ++j) {
            const int t = tb + j;
            const int tn = min(t + 4, T_FRAMES - 1);
            float4 nxa = *(const float4*)(X + (size_t)tn * F_STRIDE);
            float4 nya = *(const float4*)(Y + (size_t)tn * F_STRIDE);

            float xa[4] = {cxa.x, cxa.y, cxa.z, cxa.w};
            float ya[4] = {cya.x, cya.y, cya.z, cya.w};

            // add row t+3 (prefetched)
            #pragma unroll
            for (int c = 0; c < 4; ++c) {
                sx[c] += xa[c]; sy[c] += ya[c];
                s2[c] += xa[c]*xa[c] + ya[c]*ya[c];
                sxy[c] += xa[c]*ya[c];
            }

            float wx[4], wy[4], w2[4], wxy[4];
            HWIN7(sx,  wx);
            HWIN7(sy,  wy);
            HWIN7(s2,  w2);
            HWIN7(sxy, wxy);

            const bool live = (t < t1);
            float rowacc = 0.0f;
            #pragma unroll
            for (int c = 0; c < 4; ++c) {
                if (live && lane_ok && (fo + c <= 1021)) {
                    float p = wx[c] * wy[c];                       // wx*wy
                    float q = fmaf(wx[c], wx[c], wy[c]*wy[c]);     // wx^2+wy^2
                    float r = fmaf(49.f, wxy[c], -p);              // 49wxy - p
                    float s = fmaf(49.f, w2[c],  -q);              // 49w2  - q
                    float num = fmaf(2.f, p, K1_) * fmaf(2.f, r, K2_);
                    float den = (q + K1_) * (s + K2_);
                    rowacc = fmaf(num, __builtin_amdgcn_rcpf(den), rowacc);
                }
            }
            acc += (double)rowacc;

            // subtract row t-3 from the ring (static slot j), store new row
            #pragma unroll
            for (int c = 0; c < 4; ++c) {
                float bx_ = rgx[j][c], by_ = rgy[j][c];
                sx[c]  -= bx_;      sy[c]  -= by_;
                s2[c]  -= bx_*bx_ + by_*by_;
                sxy[c] -= bx_*by_;
                rgx[j][c] = xa[c];  rgy[j][c] = ya[c];
            }

            cxa = nxa; cya = nya;
        }
    }

    #pragma unroll
    for (int off = 32; off > 0; off >>= 1) acc += __shfl_down(acc, off, 64);
    if (lane == 0) {
        atomicAdd(&out[ch0 + cg], (float)(acc / (395.0 * 1019.0)));
    }
}

extern "C" void kernel_launch(void* const* d_in, const int* in_sizes, int n_in,
                              void* d_out, int out_size, void* d_ws, size_t ws_size,
                              hipStream_t stream) {
    const float* x0 = (const float*)d_in[0];   // output
    const float* x1 = (const float*)d_in[1];   // target
    float* out = (float*)d_out;
    float* ws  = (float*)d_ws;

    const size_t table_bytes  = (size_t)SPEC_OFF * sizeof(float);
    const size_t per_ch_bytes = (size_t)2 * T_FRAMES * F_STRIDE * sizeof(float);
    int G = (int)((ws_size - table_bytes) / per_ch_bytes);
    if (G > N_CH) G = N_CH;
    if (G < 1)    G = 1;

    init_tables_kernel<<<dim3(16), dim3(256), 0, stream>>>(ws, out);

    if (G >= N_CH) {
        // single swizzled 64-channel stft + single ssim (3 dispatches total)
        stft_mag_kernel<<<dim3(T_FRAMES * 64), dim3(256), 0, stream>>>(x0, x1, ws, 0, 0, N_CH, 1);
        const int nwaves = N_CH * BANDS * NCHUNKS_R;
        ssim_kernel<<<dim3((nwaves + 3) / 4), dim3(256), 0, stream>>>(ws, out, 0, N_CH);
    } else {
        for (int ch0 = 0; ch0 < N_CH; ch0 += G) {
            const int nch = (N_CH - ch0 < G) ? (N_CH - ch0) : G;
            stft_mag_kernel<<<dim3(T_FRAMES, nch), dim3(256), 0, stream>>>(x0, x1, ws, ch0, ch0, nch, 0);
            const int nwaves = nch * BANDS * NCHUNKS_R;
            ssim_kernel<<<dim3((nwaves + 3) / 4), dim3(256), 0, stream>>>(ws, out, ch0, nch);
        }
    }
}